// Round 6
// baseline (670.397 us; speedup 1.0000x reference)
//
#include <hip/hip_runtime.h>
#include <stdint.h>

#define N      8192
#define FEAT   512
#define HID    64
#define NH     4
#define C1     256          // NH*HID
#define PCH    80           // per-head c width incl. Z tile (64 data + 16)
#define TC     320          // NH*PCH
#define C2     32           // phase-B c width (16 data + 16 Z tile)

typedef __attribute__((ext_vector_type(8))) short bf16x8;
typedef __attribute__((ext_vector_type(4))) float f32x4;
typedef __attribute__((ext_vector_type(4))) uint32_t u32x4;

__device__ __forceinline__ float b2f(uint16_t u){
  uint32_t x = ((uint32_t)u) << 16;
  return __builtin_bit_cast(float, x);
}
__device__ __forceinline__ uint16_t f2b(float f){
  uint32_t x = __builtin_bit_cast(uint32_t, f);
  return (uint16_t)((x + 0x8000u) >> 16);
}
// pack two f32 -> (bf16(a) | bf16(b)<<16) via v_perm  (round-half-up)
__device__ __forceinline__ uint32_t pack_bf2(float a, float b){
  uint32_t ua = __builtin_bit_cast(uint32_t, a) + 0x8000u;
  uint32_t ub = __builtin_bit_cast(uint32_t, b) + 0x8000u;
  return __builtin_amdgcn_perm(ub, ua, 0x07060302);
}
__device__ __forceinline__ float lo_bf(uint32_t d){
  return __builtin_bit_cast(float, d << 16);
}
__device__ __forceinline__ float hi_bf(uint32_t d){
  return __builtin_bit_cast(float, d & 0xFFFF0000u);
}

// ---------------------------------------------------------------- kA: adj (int 0/1) -> bitmask adjbT[jw][i]
__global__ __launch_bounds__(256) void kA_bits(const int* __restrict__ adj, uint32_t* __restrict__ adjbT){
  int bid = blockIdx.x;               // 8192 blocks
  int iband = bid & 127, jwq = bid >> 7;
  int t = threadIdx.x;
  int i  = iband * 64 + (t & 63);
  int jw = jwq * 4 + (t >> 6);
  const int4* ap = (const int4*)(adj + (size_t)i * N + jw * 32);
  uint32_t w = 0;
  #pragma unroll
  for (int e = 0; e < 8; ++e){
    int4 v = ap[e];
    uint32_t nib = (uint32_t)(v.x & 1) | ((uint32_t)(v.y & 1) << 1)
                 | ((uint32_t)(v.z & 1) << 2) | ((uint32_t)(v.w & 1) << 3);
    w |= nib << (4 * e);
  }
  adjbT[(size_t)jw * N + i] = w;
}

// ---------------------------------------------------------------- kX: x fp32 -> xb bf16
__global__ void kX_cast(const float* __restrict__ x, uint16_t* __restrict__ xb){
  int idx = (blockIdx.x * 256 + threadIdx.x) * 8;   // 2048 blocks
  float4 a = *(const float4*)(x + idx);
  float4 b = *(const float4*)(x + idx + 4);
  uint4 v = {pack_bf2(a.x, a.y), pack_bf2(a.z, a.w), pack_bf2(b.x, b.y), pack_bf2(b.z, b.w)};
  *(uint4*)(xb + idx) = v;
}

// ---------------------------------------------------------------- kW: Wh -> WhTb[k][cc][f] bf16 ; Wo -> WoTb[c][f] bf16
__global__ void kW_cast(const float* __restrict__ Wh, const float* __restrict__ Wo,
                        uint16_t* __restrict__ WhTb, uint16_t* __restrict__ WoTb){
  int idx = blockIdx.x * 256 + threadIdx.x;         // 528 blocks
  if (idx < 131072){
    int k = idx >> 15, r = idx & 32767;
    int cc = r >> 9, f = r & 511;
    WhTb[idx] = f2b(Wh[k * 32768 + f * 64 + cc]);
  } else if (idx < 131072 + 4096){
    int j = idx - 131072;                           // c = j>>8, f = j&255
    WoTb[j] = f2b(Wo[(j & 255) * 16 + (j >> 8)]);
  }
}

// ---------------------------------------------------------------- k1m: H = xb @ WhTb (MFMA) -> HT bf16 + f1,f2 fp32
// grid 128 x 256: block = 64 rows; wave = 16 rows x 256 cols
__global__ __launch_bounds__(256) void k1m(const uint16_t* __restrict__ xb,
    const uint16_t* __restrict__ WhTb, const float* __restrict__ ah,
    uint16_t* __restrict__ HT, float* __restrict__ f1, float* __restrict__ f2)
{
  const int t = threadIdx.x, w = t >> 6, lane = t & 63;
  const int m = lane & 15, q = lane >> 4;
  const int row0 = blockIdx.x * 64 + w * 16;
  f32x4 acc[16] = {};
  const uint16_t* arow = xb + (size_t)(row0 + m) * 512 + q * 8;
  for (int kk = 0; kk < 512; kk += 32){
    bf16x8 af = *(const bf16x8*)(arow + kk);
    #pragma unroll
    for (int ct = 0; ct < 16; ++ct){
      bf16x8 bf = *(const bf16x8*)(WhTb + (size_t)(ct * 16 + m) * 512 + kk + q * 8);
      acc[ct] = __builtin_amdgcn_mfma_f32_16x16x32_bf16(af, bf, acc[ct], 0, 0, 0);
    }
  }
  #pragma unroll
  for (int ct = 0; ct < 16; ++ct){
    int col = ct * 16 + m;
    uint2 v = {pack_bf2(acc[ct][0], acc[ct][1]), pack_bf2(acc[ct][2], acc[ct][3])};
    *(uint2*)(HT + (size_t)(col >> 6) * (PCH * N) + (size_t)(col & 63) * N + row0 + q * 4) = v;
  }
  float a1v[16], a2v[16];
  #pragma unroll
  for (int ct = 0; ct < 16; ++ct){
    int col = ct * 16 + m;
    a1v[ct] = ah[(col >> 6) * 128 + (col & 63)];
    a2v[ct] = ah[(col >> 6) * 128 + 64 + (col & 63)];
  }
  #pragma unroll
  for (int hh = 0; hh < 4; ++hh){
    #pragma unroll
    for (int r = 0; r < 4; ++r){
      float v1 = 0.f, v2 = 0.f;
      #pragma unroll
      for (int c4 = 0; c4 < 4; ++c4){
        v1 += acc[hh * 4 + c4][r] * a1v[hh * 4 + c4];
        v2 += acc[hh * 4 + c4][r] * a2v[hh * 4 + c4];
      }
      #pragma unroll
      for (int off = 1; off < 16; off <<= 1){
        v1 += __shfl_xor(v1, off);
        v2 += __shfl_xor(v2, off);
      }
      if (m == 0){
        int row = row0 + q * 4 + r;
        f1[hh * N + row] = v1;
        f2[hh * N + row] = v2;
      }
    }
  }
}

// ---------------------------------------------------------------- kE: f1,f2 -> e1p (f32 pair), e2b (bf16 packed)
__global__ void kE_exp(const float* __restrict__ f1, const float* __restrict__ f2,
                       float2* __restrict__ e1p, uint32_t* __restrict__ e2b){
  int idx = blockIdx.x * 256 + threadIdx.x;      // 32768
  float v1 = f1[idx], v2 = f2[idx];
  e1p[idx] = make_float2(__expf(v1), __expf(0.2f * v1));
  e2b[idx] = pack_bf2(__expf(v2), __expf(0.2f * v2));
}

// ---------------------------------------------------------------- k2b: HT rows 64..79 (ones + zeros)
__global__ void k2b_fill(uint16_t* __restrict__ HT){
  int fidx = blockIdx.x * 256 + threadIdx.x;      // 65536 uint4 units
  int k = fidx >> 14;
  int rem = fidx & 16383;
  int p = 64 + (rem >> 10);
  int i0 = (rem & 1023) << 3;
  uint32_t w = (p == 64) ? 0x3F803F80u : 0u;
  uint4 v = {w, w, w, w};
  *((uint4*)(HT + (size_t)k * (PCH * N) + (size_t)p * N + i0)) = v;
}

// ---------------------------------------------------------------- k3: phase-A, 32 rows/wave, dbuf, 3 waves/SIMD
// grid: 64 ibl x 4 head x 4 js = 1024 blocks x 256 th
__global__ __launch_bounds__(256, 3) void k3_attA(const uint32_t* __restrict__ adjbT,
    const uint16_t* __restrict__ HT, const float2* __restrict__ e1p,
    const uint32_t* __restrict__ e2b, float* __restrict__ accA)
{
  const int t    = threadIdx.x;
  const int bid  = blockIdx.x;
  const int js   = bid & 3;
  const int head = (bid >> 2) & 3;
  const int ibl  = bid >> 4;             // 0..63
  const int w    = t >> 6;
  const int lane = t & 63;
  const int m    = lane & 15;
  const int q    = lane >> 4;
  const int gi0  = ibl * 128 + w * 32;

  float2 e1a = e1p[(size_t)head * N + gi0 + m];
  float2 e1b = e1p[(size_t)head * N + gi0 + 16 + m];

  const uint16_t* Hb = HT + (size_t)head * (PCH * N) + (size_t)m * N + q * 8;
  const uint32_t* Mb = adjbT + gi0 + m;
  const uint32_t* Eb = e2b + (size_t)head * N + js * 2048 + q * 8;

  f32x4 acc[2][5] = {};

  uint4    ed[2][2];
  uint32_t mw[2][2];
  bf16x8   bq[2][5];

  auto lset = [&](int buf, int jc){
    const int gj = js * 2048 + jc * 32;
    const int jw = gj >> 5;
    ed[buf][0] = *(const uint4*)(Eb + jc * 32);
    ed[buf][1] = *(const uint4*)(Eb + jc * 32 + 4);
    mw[buf][0] = Mb[(size_t)jw * N];
    mw[buf][1] = Mb[(size_t)jw * N + 16];
    #pragma unroll
    for (int ct = 0; ct < 5; ++ct)
      bq[buf][ct] = *(const bf16x8*)(Hb + (size_t)(ct * 16) * N + gj);
  };
  auto comp = [&](int buf){
    uint32_t sh0 = mw[buf][0] >> (q * 8);
    uint32_t sh1 = mw[buf][1] >> (q * 8);
    u32x4 pk0, pk1;
    #pragma unroll
    for (int p = 0; p < 4; ++p){
      uint32_t d0 = (p & 1) ? ed[buf][p >> 1].z : ed[buf][p >> 1].x;
      uint32_t d1 = (p & 1) ? ed[buf][p >> 1].w : ed[buf][p >> 1].y;
      float e2x = lo_bf(d0), e2sx = hi_bf(d0);
      float e2y = lo_bf(d1), e2sy = hi_bf(d1);
      float wa0 = fmaxf(e1a.x * e2x, e1a.y * e2sx);
      float wb0 = fmaxf(e1a.x * e2y, e1a.y * e2sy);
      wa0 = ((sh0 >> (2 * p)) & 1u) ? wa0 : 0.f;
      wb0 = ((sh0 >> (2 * p)) & 2u) ? wb0 : 0.f;
      pk0[p] = pack_bf2(wa0, wb0);
      float wa1 = fmaxf(e1b.x * e2x, e1b.y * e2sx);
      float wb1 = fmaxf(e1b.x * e2y, e1b.y * e2sy);
      wa1 = ((sh1 >> (2 * p)) & 1u) ? wa1 : 0.f;
      wb1 = ((sh1 >> (2 * p)) & 2u) ? wb1 : 0.f;
      pk1[p] = pack_bf2(wa1, wb1);
    }
    bf16x8 af0 = __builtin_bit_cast(bf16x8, pk0);
    bf16x8 af1 = __builtin_bit_cast(bf16x8, pk1);
    #pragma unroll
    for (int ct = 0; ct < 5; ++ct){
      acc[0][ct] = __builtin_amdgcn_mfma_f32_16x16x32_bf16(af0, bq[buf][ct], acc[0][ct], 0, 0, 0);
      acc[1][ct] = __builtin_amdgcn_mfma_f32_16x16x32_bf16(af1, bq[buf][ct], acc[1][ct], 0, 0, 0);
    }
  };

  lset(0, 0);
  for (int jc = 0; jc < 64; jc += 2){
    lset(1, jc + 1);
    comp(0);
    lset(0, jc + 2 < 64 ? jc + 2 : 62);   // dummy reload on last
    comp(1);
  }

  #pragma unroll
  for (int r = 0; r < 2; ++r)
    #pragma unroll
    for (int ct = 0; ct < 5; ++ct)
      #pragma unroll
      for (int reg = 0; reg < 4; ++reg){
        int gi = gi0 + r * 16 + q * 4 + reg;
        int c  = head * PCH + ct * 16 + m;
        accA[((size_t)js * N + gi) * TC + c] = acc[r][ct][reg];
      }
}

// ---------------------------------------------------------------- k4: reduce partials -> xcat (lrelu 0.01)
__global__ void k4_redA(const float* __restrict__ accA, uint16_t* __restrict__ xcat){
  int i = blockIdx.x;
  int t = threadIdx.x;
  int k = t >> 6, cc = t & 63;
  size_t base = (size_t)i * TC + k * PCH;
  float v = 0.f, Z = 0.f;
  #pragma unroll
  for (int js = 0; js < 4; ++js){
    const float* p = accA + (size_t)js * N * TC + base;
    v += p[cc];
    Z += p[64];
  }
  float r = v / Z;
  xcat[(size_t)i * C1 + t] = f2b(fmaxf(r, 0.01f * r));
}

// ---------------------------------------------------------------- k5m: h2 = xcat @ WoTb (MFMA) -> h2T + e1op/e2ob
// grid 128 x 256: wave = 16 rows x 16 cols
__global__ __launch_bounds__(256) void k5m(const uint16_t* __restrict__ xcat,
    const uint16_t* __restrict__ WoTb, const float* __restrict__ ao,
    uint16_t* __restrict__ h2T, float2* __restrict__ e1op, uint32_t* __restrict__ e2ob)
{
  const int t = threadIdx.x, w = t >> 6, lane = t & 63;
  const int m = lane & 15, q = lane >> 4;
  const int row0 = blockIdx.x * 64 + w * 16;
  f32x4 acc = {0.f, 0.f, 0.f, 0.f};
  const uint16_t* arow = xcat + (size_t)(row0 + m) * 256 + q * 8;
  const uint16_t* brow = WoTb + m * 256 + q * 8;
  #pragma unroll
  for (int kk = 0; kk < 256; kk += 32){
    bf16x8 af = *(const bf16x8*)(arow + kk);
    bf16x8 bf = *(const bf16x8*)(brow + kk);
    acc = __builtin_amdgcn_mfma_f32_16x16x32_bf16(af, bf, acc, 0, 0, 0);
  }
  uint2 v = {pack_bf2(acc[0], acc[1]), pack_bf2(acc[2], acc[3])};
  *(uint2*)(h2T + (size_t)m * N + row0 + q * 4) = v;
  float aov1 = ao[m], aov2 = ao[16 + m];
  #pragma unroll
  for (int r = 0; r < 4; ++r){
    float v1 = acc[r] * aov1, v2 = acc[r] * aov2;
    #pragma unroll
    for (int off = 1; off < 16; off <<= 1){
      v1 += __shfl_xor(v1, off);
      v2 += __shfl_xor(v2, off);
    }
    if (m == 0){
      int row = row0 + q * 4 + r;
      e1op[row] = make_float2(__expf(v1), __expf(0.2f * v1));
      e2ob[row] = pack_bf2(__expf(v2), __expf(0.2f * v2));
    }
  }
}

// ---------------------------------------------------------------- kF: h2T rows 16..31 (ones + zeros)
__global__ void kF_fill(uint16_t* __restrict__ h2T){
  int idx = blockIdx.x * 256 + threadIdx.x;      // 16384 uint4 units, 64 blocks
  int p = 16 + (idx >> 10);
  int i0 = (idx & 1023) << 3;
  uint32_t w = (p == 16) ? 0x3F803F80u : 0u;
  uint4 v = {w, w, w, w};
  *((uint4*)(h2T + (size_t)p * N + i0)) = v;
}

// ---------------------------------------------------------------- k6: phase-B, 32 rows/wave, js=16, dbuf
// grid: 64 ibl x 16 js = 1024 blocks x 256 th
__global__ __launch_bounds__(256, 4) void k6_attB(const uint32_t* __restrict__ adjbT,
    const uint16_t* __restrict__ h2T, const float2* __restrict__ e1op,
    const uint32_t* __restrict__ e2ob, float* __restrict__ accB)
{
  const int t    = threadIdx.x;
  const int bid  = blockIdx.x;
  const int js   = bid & 15;
  const int ibl  = bid >> 4;             // 0..63
  const int w    = t >> 6;
  const int lane = t & 63;
  const int m    = lane & 15;
  const int q    = lane >> 4;
  const int gi0  = ibl * 128 + w * 32;

  float2 e1a = e1op[gi0 + m];
  float2 e1b = e1op[gi0 + 16 + m];

  const uint16_t* Hb = h2T + (size_t)m * N + q * 8;
  const uint32_t* Mb = adjbT + gi0 + m;
  const uint32_t* Eb = e2ob + js * 512 + q * 8;

  f32x4 acc[2][2] = {};

  uint4    ed[2][2];
  uint32_t mw[2][2];
  bf16x8   bq[2][2];

  auto lset = [&](int buf, int jc){
    const int gj = js * 512 + jc * 32;
    const int jw = gj >> 5;
    ed[buf][0] = *(const uint4*)(Eb + jc * 32);
    ed[buf][1] = *(const uint4*)(Eb + jc * 32 + 4);
    mw[buf][0] = Mb[(size_t)jw * N];
    mw[buf][1] = Mb[(size_t)jw * N + 16];
    bq[buf][0] = *(const bf16x8*)(Hb + gj);
    bq[buf][1] = *(const bf16x8*)(Hb + (size_t)16 * N + gj);
  };
  auto comp = [&](int buf){
    uint32_t sh0 = mw[buf][0] >> (q * 8);
    uint32_t sh1 = mw[buf][1] >> (q * 8);
    u32x4 pk0, pk1;
    #pragma unroll
    for (int p = 0; p < 4; ++p){
      uint32_t d0 = (p & 1) ? ed[buf][p >> 1].z : ed[buf][p >> 1].x;
      uint32_t d1 = (p & 1) ? ed[buf][p >> 1].w : ed[buf][p >> 1].y;
      float e2x = lo_bf(d0), e2sx = hi_bf(d0);
      float e2y = lo_bf(d1), e2sy = hi_bf(d1);
      float wa0 = fmaxf(e1a.x * e2x, e1a.y * e2sx);
      float wb0 = fmaxf(e1a.x * e2y, e1a.y * e2sy);
      wa0 = ((sh0 >> (2 * p)) & 1u) ? wa0 : 0.f;
      wb0 = ((sh0 >> (2 * p)) & 2u) ? wb0 : 0.f;
      pk0[p] = pack_bf2(wa0, wb0);
      float wa1 = fmaxf(e1b.x * e2x, e1b.y * e2sx);
      float wb1 = fmaxf(e1b.x * e2y, e1b.y * e2sy);
      wa1 = ((sh1 >> (2 * p)) & 1u) ? wa1 : 0.f;
      wb1 = ((sh1 >> (2 * p)) & 2u) ? wb1 : 0.f;
      pk1[p] = pack_bf2(wa1, wb1);
    }
    bf16x8 af0 = __builtin_bit_cast(bf16x8, pk0);
    bf16x8 af1 = __builtin_bit_cast(bf16x8, pk1);
    #pragma unroll
    for (int ct = 0; ct < 2; ++ct){
      acc[0][ct] = __builtin_amdgcn_mfma_f32_16x16x32_bf16(af0, bq[buf][ct], acc[0][ct], 0, 0, 0);
      acc[1][ct] = __builtin_amdgcn_mfma_f32_16x16x32_bf16(af1, bq[buf][ct], acc[1][ct], 0, 0, 0);
    }
  };

  lset(0, 0);
  for (int jc = 0; jc < 16; jc += 2){
    lset(1, jc + 1);
    comp(0);
    lset(0, jc + 2 < 16 ? jc + 2 : 14);
    comp(1);
  }

  #pragma unroll
  for (int r = 0; r < 2; ++r)
    #pragma unroll
    for (int ct = 0; ct < 2; ++ct)
      #pragma unroll
      for (int reg = 0; reg < 4; ++reg){
        int gi = gi0 + r * 16 + q * 4 + reg;
        accB[((size_t)js * N + gi) * C2 + ct * 16 + m] = acc[r][ct][reg];
      }
}

// ---------------------------------------------------------------- k7: reduce -> out (fp32)
__global__ void k7_redB(const float* __restrict__ accB, float* __restrict__ out){
  int idx = blockIdx.x * 256 + threadIdx.x;   // 131072
  int i = idx >> 4, c = idx & 15;
  float v = 0.f, Z = 0.f;
  #pragma unroll
  for (int js = 0; js < 16; ++js){
    const float* p = accB + ((size_t)js * N + i) * C2;
    v += p[c];
    Z += p[16];
  }
  out[idx] = v / Z;
}

// ================================================================ launch
extern "C" void kernel_launch(void* const* d_in, const int* in_sizes, int n_in,
                              void* d_out, int out_size, void* d_ws, size_t ws_size,
                              hipStream_t stream)
{
  const float* x   = (const float*)d_in[0];
  const int*   adj = (const int*)d_in[1];
  const float* Wh  = (const float*)d_in[2];
  const float* ah  = (const float*)d_in[3];
  const float* Wo  = (const float*)d_in[4];
  const float* ao  = (const float*)d_in[5];
  float* out = (float*)d_out;

  char* ws = (char*)d_ws;
  uint16_t* xb    = (uint16_t*)(ws);                 // 8 MB
  uint16_t* WhTb  = (uint16_t*)(ws + 8388608);       // 256 KB
  uint16_t* WoTb  = (uint16_t*)(ws + 8650752);       // 8 KB
  uint16_t* HT    = (uint16_t*)(ws + 8658944);       // 5 MB  [4][80][8192]
  float*    f1    = (float*)   (ws + 13901824);      // 128 KB
  float*    f2    = (float*)   (ws + 14032896);      // 128 KB
  float2*   e1p   = (float2*)  (ws + 14163968);      // 256 KB [4][8192]
  uint32_t* e2b   = (uint32_t*)(ws + 14426112);      // 128 KB [4][8192]
  float*    accA  = (float*)   (ws + 14557184);      // 40 MB [4][8192][320]
  uint16_t* xcat  = (uint16_t*)(ws + 56500224);      // 4 MB
  uint16_t* h2T   = (uint16_t*)(ws + 60694528);      // 512 KB [32][8192]
  float2*   e1op  = (float2*)  (ws + 61218816);      // 64 KB
  uint32_t* e2ob  = (uint32_t*)(ws + 61284352);      // 32 KB
  float*    accB  = (float*)   (ws + 61317120);      // 16 MB [16][8192][32]
  uint32_t* adjbT = (uint32_t*)(ws + 78094336);      // 8 MB [256][8192]  (end 86482944)

  hipLaunchKernelGGL(kA_bits,  dim3(8192), dim3(256), 0, stream, adj, adjbT);
  hipLaunchKernelGGL(kX_cast,  dim3(2048), dim3(256), 0, stream, x, xb);
  hipLaunchKernelGGL(kW_cast,  dim3(528),  dim3(256), 0, stream, Wh, Wo, WhTb, WoTb);
  hipLaunchKernelGGL(k2b_fill, dim3(256),  dim3(256), 0, stream, HT);
  hipLaunchKernelGGL(k1m,      dim3(128),  dim3(256), 0, stream, xb, WhTb, ah, HT, f1, f2);
  hipLaunchKernelGGL(kE_exp,   dim3(128),  dim3(256), 0, stream, f1, f2, e1p, e2b);
  hipLaunchKernelGGL(k3_attA,  dim3(1024), dim3(256), 0, stream, adjbT, HT, e1p, e2b, accA);
  hipLaunchKernelGGL(k4_redA,  dim3(8192), dim3(256), 0, stream, accA, xcat);
  hipLaunchKernelGGL(k5m,      dim3(128),  dim3(256), 0, stream, xcat, WoTb, ao, h2T, e1op, e2ob);
  hipLaunchKernelGGL(kF_fill,  dim3(64),   dim3(256), 0, stream, h2T);
  hipLaunchKernelGGL(k6_attB,  dim3(1024), dim3(256), 0, stream, adjbT, h2T, e1op, e2ob, accB);
  hipLaunchKernelGGL(k7_redB,  dim3(512),  dim3(256), 0, stream, accB, out);
}